// Round 11
// baseline (285.455 us; speedup 1.0000x reference)
//
#include <hip/hip_runtime.h>

// ---------------------------------------------------------------------------
// TemporalDifferentModuleMSDeformAttnVIZ — MI355X (gfx950)
// Round 11: (1) query pre-converted to bf16 (qbf in d_out scratch) -> proj
// GEMM staging branch-free bf16 (tests "GEMM staging VALU" theory for the
// invariant ~156us non-sampler chunk); (2) transpose+convert fused (prep_k);
// (3) sampler launch_bounds (256,5) (occ 50%->62%, VGPR cap 102, no spill).
// Constants: D=256 NH=8 DH=32 L=4 NCP=4 TW=2 NTP=2 P=8
// Levels (T*H, W): TH={192,96,48,24} W={64,32,16,8} starts={0,12288,15360,16128}
// Lq=16320
// ---------------------------------------------------------------------------

typedef unsigned short bfraw;
typedef __attribute__((ext_vector_type(4))) float f32x4;
typedef __attribute__((ext_vector_type(8))) short bf16x8;

__device__ __forceinline__ float bf2f(bfraw u) {
  union { unsigned int i; float f; } v; v.i = ((unsigned int)u) << 16; return v.f;
}
__device__ __forceinline__ bfraw f2bf(float f) {
  union { float f; unsigned int i; } v; v.f = f;
  unsigned int x = v.i;
  return (bfraw)((x + 0x7FFFu + ((x >> 16) & 1u)) >> 16);  // RNE
}
__device__ __forceinline__ float lo16f(unsigned int w) {
  union { unsigned int i; float f; } v; v.i = w << 16; return v.f;
}
__device__ __forceinline__ float hi16f(unsigned int w) {
  union { unsigned int i; float f; } v; v.i = w & 0xFFFF0000u; return v.f;
}
__device__ __forceinline__ float loadx(const void* p, size_t i, int f32m) {
  if (f32m) return ((const float*)p)[i];
  else      return bf2f(((const bfraw*)p)[i]);
}
__device__ __forceinline__ unsigned pk2(float a, float b) {
  return (unsigned)f2bf(a) | ((unsigned)f2bf(b) << 16);
}

// Uniform dtype vote from the first 64 B of `query`. bf16 data: low half of
// each dword is a ~N(0,1) sample, |x| in [1e-3,16) w.p. ~0.9985 -> cnt~16.
// f32 data: low halves are mantissa bits -> ~5% in range. Returns 1 = f32.
__device__ __forceinline__ int vote_f32(const void* q) {
  const unsigned* p = (const unsigned*)q;
  int cnt = 0;
#pragma unroll
  for (int i = 0; i < 16; ++i) {
    const float a = fabsf(lo16f(p[i]));
    cnt += (a > 0.0009765625f && a < 16.0f) ? 1 : 0;
  }
  return (cnt >= 8) ? 0 : 1;
}

// prep: blocks 0..1282 = weight transpose + bias concat; blocks 1283+ =
// query f32/bf16 -> bf16 qbf (dense [16320][256], lives in d_out scratch).
// WT rows 0..255 = W_v^T ; 256..1023 = Wproj^T (so|tso|aw|taw); 1024..1279 =
// W_o^T. bcat[768] f32 = b_so|b_tso|b_aw|b_taw.
__global__ __launch_bounds__(256) void prep_k(
    const void* W_v, const void* W_so, const void* W_tso,
    const void* W_aw, const void* W_taw, const void* W_o,
    const void* b_so, const void* b_tso, const void* b_aw, const void* b_taw,
    bfraw* __restrict__ WT, float* __restrict__ bcat,
    const void* __restrict__ query, bfraw* __restrict__ qbf)
{
  const int f32m = vote_f32(query);
  const int b = blockIdx.x, t = threadIdx.x;
  if (b < 1280) {
    float s;
    if (b < 256)       s = loadx(W_v, (size_t)t * 256 + b, f32m);
    else if (b < 1024) {
      const int rp = b - 256;
      if (rp < 256)      s = loadx(W_so,  (size_t)t * 256 + rp, f32m);
      else if (rp < 512) s = loadx(W_tso, (size_t)t * 256 + (rp - 256), f32m);
      else if (rp < 640) s = loadx(W_aw,  (size_t)t * 128 + (rp - 512), f32m);
      else               s = loadx(W_taw, (size_t)t * 128 + (rp - 640), f32m);
    } else               s = loadx(W_o,  (size_t)t * 256 + (b - 1024), f32m);
    WT[(size_t)b * 256 + t] = f2bf(s);
  } else if (b < 1283) {
    const int i = (b - 1280) * 256 + t;
    if (i < 768) {
      float s;
      if (i < 256)      s = loadx(b_so,  i, f32m);
      else if (i < 512) s = loadx(b_tso, i - 256, f32m);
      else if (i < 640) s = loadx(b_aw,  i - 512, f32m);
      else              s = loadx(b_taw, i - 640, f32m);
      bcat[i] = s;
    }
  } else {
    // query convert: 8 elements/thread, 2048/block; 2040 blocks exactly.
    const size_t e = ((size_t)(b - 1283) * 256 + t) * 8;
    uint4 pk;
    if (f32m) {
      const float* Qf = (const float*)query + e;
      const float4 x0 = ((const float4*)Qf)[0];
      const float4 x1 = ((const float4*)Qf)[1];
      pk.x = pk2(x0.x, x0.y); pk.y = pk2(x0.z, x0.w);
      pk.z = pk2(x1.x, x1.y); pk.w = pk2(x1.z, x1.w);
    } else {
      pk = *(const uint4*)((const bfraw*)query + e);
    }
    *(uint4*)(qbf + e) = pk;
  }
}

// Fused value + proj GEMM. 128x128 tiles, K=256, M=16320 (tail-guarded).
// blockIdx.y 0..1: value = inflat @ WvT^T + b_v    (A dtype per vote)
// blockIdx.y 2..7: proj  = qbf    @ WprojT^T + bcat (A pure bf16, branch-free)
__global__ __launch_bounds__(256) void gemmVP_k(
    const void* __restrict__ inflat, const bfraw* __restrict__ qbf,
    const bfraw* __restrict__ WT, const void* __restrict__ b_v,
    const float* __restrict__ bcat,
    bfraw* __restrict__ value, bfraw* __restrict__ proj,
    const void* __restrict__ query, int M)
{
  __shared__ bfraw As[128][40];   // [m][k], +8 pad
  __shared__ bfraw Bs[128][40];   // [n][k]
  const int f32m = vote_f32(query);
  const int y = blockIdx.y;
  const void* A; bfraw* C; int ldc, wtb, colb, bmode, a_f32;
  if (y < 2) { A = inflat; C = value; ldc = 256; wtb = y * 128;             colb = y * 128;         bmode = 1; a_f32 = f32m; }
  else       { A = qbf;    C = proj;  ldc = 768; wtb = 256 + (y - 2) * 128; colb = (y - 2) * 128;   bmode = 0; a_f32 = 0;    }

  const int bm = blockIdx.x * 128;
  const int tid = threadIdx.x;
  const int wave = tid >> 6, lane = tid & 63;
  const int quad = lane >> 4, l16 = lane & 15;
  const int mb = (wave >> 1) * 64, nb = (wave & 1) * 64;
  const int srow = tid >> 1;
  const int sk = (tid & 1) * 16;

  int lr = bm + srow; if (lr >= M) lr = M - 1;
  const size_t aoff = (size_t)lr * 256;

  f32x4 acc[4][4] = {{{0.f}}};

  for (int k0 = 0; k0 < 256; k0 += 32) {
    uint4 pa0, pa1;
    if (a_f32) {
      const float* Af = (const float*)A + aoff + (k0 + sk);
      const float4 x0 = ((const float4*)Af)[0];
      const float4 x1 = ((const float4*)Af)[1];
      const float4 x2 = ((const float4*)Af)[2];
      const float4 x3 = ((const float4*)Af)[3];
      pa0.x = pk2(x0.x, x0.y); pa0.y = pk2(x0.z, x0.w);
      pa0.z = pk2(x1.x, x1.y); pa0.w = pk2(x1.z, x1.w);
      pa1.x = pk2(x2.x, x2.y); pa1.y = pk2(x2.z, x2.w);
      pa1.z = pk2(x3.x, x3.y); pa1.w = pk2(x3.z, x3.w);
    } else {
      const bfraw* Ab = (const bfraw*)A + aoff + (k0 + sk);
      pa0 = ((const uint4*)Ab)[0];
      pa1 = ((const uint4*)Ab)[1];
    }
    const bfraw* Bb = WT + (size_t)(wtb + srow) * 256 + (k0 + sk);
    const uint4 pb0 = ((const uint4*)Bb)[0];
    const uint4 pb1 = ((const uint4*)Bb)[1];
    *(uint4*)&As[srow][sk]     = pa0;
    *(uint4*)&As[srow][sk + 8] = pa1;
    *(uint4*)&Bs[srow][sk]     = pb0;
    *(uint4*)&Bs[srow][sk + 8] = pb1;
    __syncthreads();

    bf16x8 af[4], bf[4];
#pragma unroll
    for (int i = 0; i < 4; ++i)
      af[i] = *(const bf16x8*)&As[mb + i * 16 + l16][quad * 8];
#pragma unroll
    for (int j = 0; j < 4; ++j)
      bf[j] = *(const bf16x8*)&Bs[nb + j * 16 + l16][quad * 8];
#pragma unroll
    for (int i = 0; i < 4; ++i)
#pragma unroll
      for (int j = 0; j < 4; ++j)
        acc[i][j] = __builtin_amdgcn_mfma_f32_16x16x32_bf16(af[i], bf[j], acc[i][j], 0, 0, 0);
    __syncthreads();
  }

#pragma unroll
  for (int j = 0; j < 4; ++j) {
    const int col = colb + nb + j * 16 + l16;
    const float bb = bmode ? loadx(b_v, col, f32m) : bcat[col];
#pragma unroll
    for (int i = 0; i < 4; ++i) {
#pragma unroll
      for (int r = 0; r < 4; ++r) {
        const int lrow = bm + mb + i * 16 + quad * 4 + r;
        if (lrow < M) C[(size_t)lrow * ldc + col] = f2bf(acc[i][j][r] + bb);
      }
    }
  }
}

// O-projection GEMM: out[0..M) = core @ W_o + b_o; core = proj cols [0,256)
// (bf16, stride 768, sampler overlay). C dtype per vote (overwrites qbf scratch).
__global__ __launch_bounds__(256) void gemmO_k(
    const bfraw* __restrict__ proj, const bfraw* __restrict__ WT,
    const void* __restrict__ b_o, void* __restrict__ Cout,
    const void* __restrict__ query, int M)
{
  __shared__ bfraw As[128][40];
  __shared__ bfraw Bs[128][40];
  const int f32m = vote_f32(query);
  const int bm = blockIdx.x * 128;
  const int bn = blockIdx.y * 128;
  const int tid = threadIdx.x;
  const int wave = tid >> 6, lane = tid & 63;
  const int quad = lane >> 4, l16 = lane & 15;
  const int mb = (wave >> 1) * 64, nb = (wave & 1) * 64;
  const int srow = tid >> 1;
  const int sk = (tid & 1) * 16;

  int lr = bm + srow; if (lr >= M) lr = M - 1;
  const size_t aoff = (size_t)lr * 768;

  f32x4 acc[4][4] = {{{0.f}}};

  for (int k0 = 0; k0 < 256; k0 += 32) {
    const bfraw* Ab = proj + aoff + (k0 + sk);
    const uint4 pa0 = ((const uint4*)Ab)[0];
    const uint4 pa1 = ((const uint4*)Ab)[1];
    const bfraw* Bb = WT + (size_t)(1024 + bn + srow) * 256 + (k0 + sk);
    const uint4 pb0 = ((const uint4*)Bb)[0];
    const uint4 pb1 = ((const uint4*)Bb)[1];
    *(uint4*)&As[srow][sk]     = pa0;
    *(uint4*)&As[srow][sk + 8] = pa1;
    *(uint4*)&Bs[srow][sk]     = pb0;
    *(uint4*)&Bs[srow][sk + 8] = pb1;
    __syncthreads();

    bf16x8 af[4], bf[4];
#pragma unroll
    for (int i = 0; i < 4; ++i)
      af[i] = *(const bf16x8*)&As[mb + i * 16 + l16][quad * 8];
#pragma unroll
    for (int j = 0; j < 4; ++j)
      bf[j] = *(const bf16x8*)&Bs[nb + j * 16 + l16][quad * 8];
#pragma unroll
    for (int i = 0; i < 4; ++i)
#pragma unroll
      for (int j = 0; j < 4; ++j)
        acc[i][j] = __builtin_amdgcn_mfma_f32_16x16x32_bf16(af[i], bf[j], acc[i][j], 0, 0, 0);
    __syncthreads();
  }

#pragma unroll
  for (int j = 0; j < 4; ++j) {
    const int col = bn + nb + j * 16 + l16;
    const float bb = loadx(b_o, col, f32m);
#pragma unroll
    for (int i = 0; i < 4; ++i) {
#pragma unroll
      for (int r = 0; r < 4; ++r) {
        const int lrow = bm + mb + i * 16 + quad * 4 + r;
        if (lrow < M) {
          const float v = acc[i][j][r] + bb;
          if (f32m) ((float*)Cout)[(size_t)lrow * 256 + col] = v;
          else      ((bfraw*)Cout)[(size_t)lrow * 256 + col] = f2bf(v);
        }
      }
    }
  }
}

// Sampler, head-major: grid (2040, 8); block = 8 queries x head blockIdx.y.
// x-major dispatch sweeps heads -> live value working set ~1MB < per-XCD L2.
// proj row (768 bf16): [0,256) cso | [256,512) tso | [512,640) caw |
// [640,768) taw. Writes core slice (bf16, 32ch) over prow[h*32..h*32+32).
// (256,5): VGPR cap 102, occupancy 62% — batch-16 gather lives ~70 VGPR,
// no spill expected (tripwire: WRITE_SIZE must stay ~11.7 MB).
__global__ __launch_bounds__(256, 5) void sampler_k(
    bfraw* __restrict__ proj, const bfraw* __restrict__ value,
    const void* __restrict__ refp, const void* __restrict__ toff,
    const void* __restrict__ query)
{
  __shared__ int   s_idx[256][4];  // clamped pixel index (always valid)
  __shared__ float s_w[256][4];    // attn*bilinear, 0 if OOB

  const int f32m = vote_f32(query);
  const int h = blockIdx.y;
  const int tid = threadIdx.x;
  const int qi = tid >> 5;         // query-in-block 0..7
  const int sp = tid & 31;         // point-in-head
  const int l = sp >> 3;           // level
  const int p = sp & 7;            // 0..3 current, 4..7 temporal
  const int qg = blockIdx.x * 8 + qi;

  const int W_i[4]  = {64, 32, 16, 8};
  const int TH_i[4] = {192, 96, 48, 24};
  const int ST_i[4] = {0, 12288, 15360, 16128};
  const float Wf  = (float)W_i[l];
  const float THf = (float)TH_i[l];

  bfraw* prow = proj + (size_t)qg * 768;

  // ---- joint softmax over 32 logits of (qg, h) — shfl in 32-lane group ----
  const float logit = (p < 4) ? bf2f(prow[512 + h * 16 + l * 4 + p])
                              : bf2f(prow[640 + h * 16 + l * 4 + (p - 4)]);
  float mx = logit;
#pragma unroll
  for (int m = 16; m >= 1; m >>= 1) mx = fmaxf(mx, __shfl_xor(mx, m));
  const float e = __expf(logit - mx);
  float ssum = e;
#pragma unroll
  for (int m = 16; m >= 1; m >>= 1) ssum += __shfl_xor(ssum, m);
  const float attn = e / ssum;

  // ---- sampling location + bilinear corner descriptors ----
  const float rx = loadx(refp, (size_t)(qg * 4 + l) * 2 + 0, f32m);
  const float ry = loadx(refp, (size_t)(qg * 4 + l) * 2 + 1, f32m);
  float ox, oy;
  if (p < 4) {
    ox = bf2f(prow[h * 32 + l * 8 + p * 2 + 0]) / Wf;
    oy = bf2f(prow[h * 32 + l * 8 + p * 2 + 1]) / THf;
  } else {
    const int pj = p - 4, tw = pj >> 1, j = pj & 1;
    ox = loadx(toff, (size_t)(qg * 4 + l) * 4 + tw * 2 + 0, f32m) +
         bf2f(prow[256 + h * 32 + l * 8 + tw * 4 + j * 2 + 0]) / Wf;
    oy = loadx(toff, (size_t)(qg * 4 + l) * 4 + tw * 2 + 1, f32m) +
         bf2f(prow[256 + h * 32 + l * 8 + tw * 4 + j * 2 + 1]) / THf;
  }
  const float x = (rx + ox) * Wf - 0.5f;   // grid_sample align_corners=False
  const float y = (ry + oy) * THf - 0.5f;
  const float x0f = floorf(x), y0f = floorf(y);
  const float lx = x - x0f, ly = y - y0f;
  const int x0 = (int)x0f, y0 = (int)y0f;
  const int Wg = W_i[l], THg = TH_i[l], ST = ST_i[l];
  const float cwx[2] = {1.f - lx, lx};
  const float cwy[2] = {1.f - ly, ly};
#pragma unroll
  for (int c = 0; c < 4; ++c) {
    const int xi = x0 + (c & 1), yi = y0 + (c >> 1);
    const bool inb = (xi >= 0) & (xi < Wg) & (yi >= 0) & (yi < THg);
    const int xc = min(max(xi, 0), Wg - 1);
    const int yc = min(max(yi, 0), THg - 1);
    s_idx[tid][c] = ST + yc * Wg + xc;
    s_w[tid][c] = inb ? (attn * cwx[c & 1] * cwy[c >> 1]) : 0.f;
  }
  __syncthreads();

  // ---- gather: thread = (qi, pt-group pg 0..7, ch-quad chq 0..3) ----
  {
    const int pg = sp >> 2;
    const int chq = sp & 3;
    const bfraw* vb = value + h * 32 + chq * 8;
    int   idx[16];
    float ww[16];
#pragma unroll
    for (int pt = 0; pt < 4; ++pt) {
      const int ds = qi * 32 + pg * 4 + pt;
#pragma unroll
      for (int c = 0; c < 4; ++c) { idx[pt * 4 + c] = s_idx[ds][c]; ww[pt * 4 + c] = s_w[ds][c]; }
    }
    uint4 vv[16];
#pragma unroll
    for (int i = 0; i < 16; ++i) vv[i] = *(const uint4*)(vb + (size_t)idx[i] * 256);
    float acc[8] = {};
#pragma unroll
    for (int i = 0; i < 16; ++i) {
      const float w = ww[i]; const uint4 v = vv[i];
      acc[0] += w * lo16f(v.x); acc[1] += w * hi16f(v.x);
      acc[2] += w * lo16f(v.y); acc[3] += w * hi16f(v.y);
      acc[4] += w * lo16f(v.z); acc[5] += w * hi16f(v.z);
      acc[6] += w * lo16f(v.w); acc[7] += w * hi16f(v.w);
    }
    // reduce over pg (lane bits 2..4 — stays within the 32-lane group)
#pragma unroll
    for (int m = 4; m <= 16; m <<= 1)
#pragma unroll
      for (int r = 0; r < 8; ++r)
        acc[r] += __shfl_xor(acc[r], m);
    if (pg == 0) {   // core overlay: prow[h*32 + chq*8 .. +8) := slice (bf16)
      uint4 pk;
      pk.x = pk2(acc[0], acc[1]);
      pk.y = pk2(acc[2], acc[3]);
      pk.z = pk2(acc[4], acc[5]);
      pk.w = pk2(acc[6], acc[7]);
      *(uint4*)(prow + h * 32 + chq * 8) = pk;
    }
  }
}

extern "C" void kernel_launch(void* const* d_in, const int* in_sizes, int n_in,
                              void* d_out, int out_size, void* d_ws, size_t ws_size,
                              hipStream_t stream)
{
  const void* query  = d_in[0];
  const void* refp   = d_in[1];
  const void* toff   = d_in[2];
  const void* inflat = d_in[3];
  const void* W_so  = d_in[6];
  const void* b_so  = d_in[7];
  const void* W_tso = d_in[8];
  const void* b_tso = d_in[9];
  const void* W_aw  = d_in[10];
  const void* b_aw  = d_in[11];
  const void* W_taw = d_in[12];
  const void* b_taw = d_in[13];
  const void* W_v   = d_in[14];
  const void* b_v   = d_in[15];
  const void* W_o   = d_in[16];
  const void* b_o   = d_in[17];

  const int Lq = 16320;
  // ws: WT bf16 [1280][256] | bcat f32[768] | value bf16 [Lq][256] |
  //     proj bf16 [Lq][768]  (~34.1 MB, same proven footprint as R10).
  // qbf (bf16 [Lq][256], 8.36 MB) lives in d_out (>= 8.36 MB both dtype
  // modes); gemmO overwrites d_out with the final result afterwards.
  const size_t WT_B   = (size_t)1280 * 256 * 2;
  const size_t BCAT_B = 768 * 4;
  const size_t VAL_B  = (size_t)Lq * 256 * 2;
  bfraw* WT    = (bfraw*)d_ws;
  float* bcat  = (float*)((char*)d_ws + WT_B);
  bfraw* value = (bfraw*)((char*)d_ws + WT_B + BCAT_B);
  bfraw* proj  = (bfraw*)((char*)d_ws + WT_B + BCAT_B + VAL_B);
  bfraw* qbf   = (bfraw*)d_out;

  const dim3 blk(256);
  prep_k<<<dim3(1283 + 2040), blk, 0, stream>>>(
      W_v, W_so, W_tso, W_aw, W_taw, W_o,
      b_so, b_tso, b_aw, b_taw, WT, bcat, query, qbf);
  gemmVP_k<<<dim3(128, 8), blk, 0, stream>>>(inflat, qbf, WT, b_v, bcat,
                                             value, proj, query, Lq);
  sampler_k<<<dim3(Lq / 8, 8), blk, 0, stream>>>(proj, value, refp, toff, query);
  gemmO_k<<<dim3(128, 2), blk, 0, stream>>>(proj, WT, b_o, d_out, query, Lq);
}

// Round 12
// 249.831 us; speedup vs baseline: 1.1426x; 1.1426x over previous
//
#include <hip/hip_runtime.h>

// ---------------------------------------------------------------------------
// TemporalDifferentModuleMSDeformAttnVIZ — MI355X (gfx950)
// Round 12: R10 revert (best: 247.6us) + DIAGNOSTIC sampler split into two
// 4-head dispatches (~46us each) so prep/gemmVP/gemmO become visible in the
// top-5 profile (they never appeared — sampler replays hogged all slots; the
// invariant ~155us non-sampler chunk is still unattributed).
// R11 lessons: launch_bounds min-waves>=5 => spill (WRITE 204MB); qbf
// pre-convert => no effect (staging-VALU hypothesis dead).
// Constants: D=256 NH=8 DH=32 L=4 NCP=4 TW=2 NTP=2 P=8
// Levels (T*H, W): TH={192,96,48,24} W={64,32,16,8} starts={0,12288,15360,16128}
// Lq=16320
// ---------------------------------------------------------------------------

typedef unsigned short bfraw;
typedef __attribute__((ext_vector_type(4))) float f32x4;
typedef __attribute__((ext_vector_type(8))) short bf16x8;

__device__ __forceinline__ float bf2f(bfraw u) {
  union { unsigned int i; float f; } v; v.i = ((unsigned int)u) << 16; return v.f;
}
__device__ __forceinline__ bfraw f2bf(float f) {
  union { float f; unsigned int i; } v; v.f = f;
  unsigned int x = v.i;
  return (bfraw)((x + 0x7FFFu + ((x >> 16) & 1u)) >> 16);  // RNE
}
__device__ __forceinline__ float lo16f(unsigned int w) {
  union { unsigned int i; float f; } v; v.i = w << 16; return v.f;
}
__device__ __forceinline__ float hi16f(unsigned int w) {
  union { unsigned int i; float f; } v; v.i = w & 0xFFFF0000u; return v.f;
}
__device__ __forceinline__ float loadx(const void* p, size_t i, int f32m) {
  if (f32m) return ((const float*)p)[i];
  else      return bf2f(((const bfraw*)p)[i]);
}
__device__ __forceinline__ unsigned pk2(float a, float b) {
  return (unsigned)f2bf(a) | ((unsigned)f2bf(b) << 16);
}

// Uniform dtype vote from the first 64 B of `query`. bf16 data: low half of
// each dword is ~N(0,1), |x| in [1e-3,16) w.p. ~0.9985 -> cnt~16. f32 data:
// low halves are mantissa bits -> ~5% in range. Returns 1 = f32.
__device__ __forceinline__ int vote_f32(const void* q) {
  const unsigned* p = (const unsigned*)q;
  int cnt = 0;
#pragma unroll
  for (int i = 0; i < 16; ++i) {
    const float a = fabsf(lo16f(p[i]));
    cnt += (a > 0.0009765625f && a < 16.0f) ? 1 : 0;
  }
  return (cnt >= 8) ? 0 : 1;
}

// Build transposed bf16 weights in ws:
// WT rows 0..255 = W_v^T ; 256..1023 = Wproj^T (so|tso|aw|taw col order);
// 1024..1279 = W_o^T. Blocks 1280..1282: bcat[768] f32 = b_so|b_tso|b_aw|b_taw.
__global__ __launch_bounds__(256) void transpose_k(
    const void* W_v, const void* W_so, const void* W_tso,
    const void* W_aw, const void* W_taw, const void* W_o,
    const void* b_so, const void* b_tso, const void* b_aw, const void* b_taw,
    bfraw* __restrict__ WT, float* __restrict__ bcat, const void* query)
{
  const int f32m = vote_f32(query);
  const int b = blockIdx.x, t = threadIdx.x;
  if (b < 1280) {
    float s;
    if (b < 256)       s = loadx(W_v, (size_t)t * 256 + b, f32m);
    else if (b < 1024) {
      const int rp = b - 256;
      if (rp < 256)      s = loadx(W_so,  (size_t)t * 256 + rp, f32m);
      else if (rp < 512) s = loadx(W_tso, (size_t)t * 256 + (rp - 256), f32m);
      else if (rp < 640) s = loadx(W_aw,  (size_t)t * 128 + (rp - 512), f32m);
      else               s = loadx(W_taw, (size_t)t * 128 + (rp - 640), f32m);
    } else               s = loadx(W_o,  (size_t)t * 256 + (b - 1024), f32m);
    WT[(size_t)b * 256 + t] = f2bf(s);
  } else {
    const int i = (b - 1280) * 256 + t;
    if (i < 768) {
      float s;
      if (i < 256)      s = loadx(b_so,  i, f32m);
      else if (i < 512) s = loadx(b_tso, i - 256, f32m);
      else if (i < 640) s = loadx(b_aw,  i - 512, f32m);
      else              s = loadx(b_taw, i - 640, f32m);
      bcat[i] = s;
    }
  }
}

// Fused value + proj GEMM. 128x128 tiles, K=256, M=16320 (tail-guarded).
// blockIdx.y 0..1: value = inflat @ WvT^T + b_v   -> value bf16 ldc 256
// blockIdx.y 2..7: proj  = query  @ WprojT^T + bcat -> proj bf16 ldc 768
__global__ __launch_bounds__(256) void gemmVP_k(
    const void* __restrict__ inflat, const void* __restrict__ query,
    const bfraw* __restrict__ WT, const void* __restrict__ b_v,
    const float* __restrict__ bcat,
    bfraw* __restrict__ value, bfraw* __restrict__ proj, int M)
{
  __shared__ bfraw As[128][40];   // [m][k], +8 pad
  __shared__ bfraw Bs[128][40];   // [n][k]
  const int f32m = vote_f32(query);
  const int y = blockIdx.y;
  const void* A; bfraw* C; int ldc, wtb, colb, bmode;
  if (y < 2) { A = inflat; C = value; ldc = 256; wtb = y * 128;             colb = y * 128;       bmode = 1; }
  else       { A = query;  C = proj;  ldc = 768; wtb = 256 + (y - 2) * 128; colb = (y - 2) * 128; bmode = 0; }

  const int bm = blockIdx.x * 128;
  const int tid = threadIdx.x;
  const int wave = tid >> 6, lane = tid & 63;
  const int quad = lane >> 4, l16 = lane & 15;
  const int mb = (wave >> 1) * 64, nb = (wave & 1) * 64;
  const int srow = tid >> 1;
  const int sk = (tid & 1) * 16;

  int lr = bm + srow; if (lr >= M) lr = M - 1;
  const size_t aoff = (size_t)lr * 256;

  f32x4 acc[4][4] = {{{0.f}}};

  for (int k0 = 0; k0 < 256; k0 += 32) {
    uint4 pa0, pa1;
    if (f32m) {
      const float* Af = (const float*)A + aoff + (k0 + sk);
      const float4 x0 = ((const float4*)Af)[0];
      const float4 x1 = ((const float4*)Af)[1];
      const float4 x2 = ((const float4*)Af)[2];
      const float4 x3 = ((const float4*)Af)[3];
      pa0.x = pk2(x0.x, x0.y); pa0.y = pk2(x0.z, x0.w);
      pa0.z = pk2(x1.x, x1.y); pa0.w = pk2(x1.z, x1.w);
      pa1.x = pk2(x2.x, x2.y); pa1.y = pk2(x2.z, x2.w);
      pa1.z = pk2(x3.x, x3.y); pa1.w = pk2(x3.z, x3.w);
    } else {
      const bfraw* Ab = (const bfraw*)A + aoff + (k0 + sk);
      pa0 = ((const uint4*)Ab)[0];
      pa1 = ((const uint4*)Ab)[1];
    }
    const bfraw* Bb = WT + (size_t)(wtb + srow) * 256 + (k0 + sk);
    const uint4 pb0 = ((const uint4*)Bb)[0];
    const uint4 pb1 = ((const uint4*)Bb)[1];
    *(uint4*)&As[srow][sk]     = pa0;
    *(uint4*)&As[srow][sk + 8] = pa1;
    *(uint4*)&Bs[srow][sk]     = pb0;
    *(uint4*)&Bs[srow][sk + 8] = pb1;
    __syncthreads();

    bf16x8 af[4], bf[4];
#pragma unroll
    for (int i = 0; i < 4; ++i)
      af[i] = *(const bf16x8*)&As[mb + i * 16 + l16][quad * 8];
#pragma unroll
    for (int j = 0; j < 4; ++j)
      bf[j] = *(const bf16x8*)&Bs[nb + j * 16 + l16][quad * 8];
#pragma unroll
    for (int i = 0; i < 4; ++i)
#pragma unroll
      for (int j = 0; j < 4; ++j)
        acc[i][j] = __builtin_amdgcn_mfma_f32_16x16x32_bf16(af[i], bf[j], acc[i][j], 0, 0, 0);
    __syncthreads();
  }

#pragma unroll
  for (int j = 0; j < 4; ++j) {
    const int col = colb + nb + j * 16 + l16;
    const float bb = bmode ? loadx(b_v, col, f32m) : bcat[col];
#pragma unroll
    for (int i = 0; i < 4; ++i) {
#pragma unroll
      for (int r = 0; r < 4; ++r) {
        const int lrow = bm + mb + i * 16 + quad * 4 + r;
        if (lrow < M) C[(size_t)lrow * ldc + col] = f2bf(acc[i][j][r] + bb);
      }
    }
  }
}

// O-projection GEMM: out[0..M) = core @ W_o + b_o; core = proj cols [0,256)
// (bf16, stride 768, sampler overlay). C dtype per vote.
__global__ __launch_bounds__(256) void gemmO_k(
    const bfraw* __restrict__ proj, const bfraw* __restrict__ WT,
    const void* __restrict__ b_o, void* __restrict__ Cout,
    const void* __restrict__ query, int M)
{
  __shared__ bfraw As[128][40];
  __shared__ bfraw Bs[128][40];
  const int f32m = vote_f32(query);
  const int bm = blockIdx.x * 128;
  const int bn = blockIdx.y * 128;
  const int tid = threadIdx.x;
  const int wave = tid >> 6, lane = tid & 63;
  const int quad = lane >> 4, l16 = lane & 15;
  const int mb = (wave >> 1) * 64, nb = (wave & 1) * 64;
  const int srow = tid >> 1;
  const int sk = (tid & 1) * 16;

  int lr = bm + srow; if (lr >= M) lr = M - 1;
  const size_t aoff = (size_t)lr * 768;

  f32x4 acc[4][4] = {{{0.f}}};

  for (int k0 = 0; k0 < 256; k0 += 32) {
    const bfraw* Ab = proj + aoff + (k0 + sk);
    const uint4 pa0 = ((const uint4*)Ab)[0];
    const uint4 pa1 = ((const uint4*)Ab)[1];
    const bfraw* Bb = WT + (size_t)(1024 + bn + srow) * 256 + (k0 + sk);
    const uint4 pb0 = ((const uint4*)Bb)[0];
    const uint4 pb1 = ((const uint4*)Bb)[1];
    *(uint4*)&As[srow][sk]     = pa0;
    *(uint4*)&As[srow][sk + 8] = pa1;
    *(uint4*)&Bs[srow][sk]     = pb0;
    *(uint4*)&Bs[srow][sk + 8] = pb1;
    __syncthreads();

    bf16x8 af[4], bf[4];
#pragma unroll
    for (int i = 0; i < 4; ++i)
      af[i] = *(const bf16x8*)&As[mb + i * 16 + l16][quad * 8];
#pragma unroll
    for (int j = 0; j < 4; ++j)
      bf[j] = *(const bf16x8*)&Bs[nb + j * 16 + l16][quad * 8];
#pragma unroll
    for (int i = 0; i < 4; ++i)
#pragma unroll
      for (int j = 0; j < 4; ++j)
        acc[i][j] = __builtin_amdgcn_mfma_f32_16x16x32_bf16(af[i], bf[j], acc[i][j], 0, 0, 0);
    __syncthreads();
  }

#pragma unroll
  for (int j = 0; j < 4; ++j) {
    const int col = bn + nb + j * 16 + l16;
    const float bb = loadx(b_o, col, f32m);
#pragma unroll
    for (int i = 0; i < 4; ++i) {
#pragma unroll
      for (int r = 0; r < 4; ++r) {
        const int lrow = bm + mb + i * 16 + quad * 4 + r;
        if (lrow < M) {
          const float v = acc[i][j][r] + bb;
          if (f32m) ((float*)Cout)[(size_t)lrow * 256 + col] = v;
          else      ((bfraw*)Cout)[(size_t)lrow * 256 + col] = f2bf(v);
        }
      }
    }
  }
}

// Sampler, head-major, SPLIT: grid (2040, 4), head = h0 + blockIdx.y; two
// dispatches (h0=0, h0=4). Block = 8 queries x 1 head. x-major dispatch
// sweeps heads -> live value working set ~1MB < per-XCD L2.
// proj row (768 bf16): [0,256) cso | [256,512) tso | [512,640) caw |
// [640,768) taw. Writes core slice (bf16, 32ch) over prow[h*32..h*32+32).
// (256,4): the empirically spill-free point (VGPR 52; >=5 spills).
__global__ __launch_bounds__(256, 4) void sampler_k(
    bfraw* __restrict__ proj, const bfraw* __restrict__ value,
    const void* __restrict__ refp, const void* __restrict__ toff,
    const void* __restrict__ query, int h0)
{
  __shared__ int   s_idx[256][4];  // clamped pixel index (always valid)
  __shared__ float s_w[256][4];    // attn*bilinear, 0 if OOB

  const int f32m = vote_f32(query);
  const int h = h0 + blockIdx.y;
  const int tid = threadIdx.x;
  const int qi = tid >> 5;         // query-in-block 0..7
  const int sp = tid & 31;         // point-in-head
  const int l = sp >> 3;           // level
  const int p = sp & 7;            // 0..3 current, 4..7 temporal
  const int qg = blockIdx.x * 8 + qi;

  const int W_i[4]  = {64, 32, 16, 8};
  const int TH_i[4] = {192, 96, 48, 24};
  const int ST_i[4] = {0, 12288, 15360, 16128};
  const float Wf  = (float)W_i[l];
  const float THf = (float)TH_i[l];

  bfraw* prow = proj + (size_t)qg * 768;

  // ---- joint softmax over 32 logits of (qg, h) — shfl in 32-lane group ----
  const float logit = (p < 4) ? bf2f(prow[512 + h * 16 + l * 4 + p])
                              : bf2f(prow[640 + h * 16 + l * 4 + (p - 4)]);
  float mx = logit;
#pragma unroll
  for (int m = 16; m >= 1; m >>= 1) mx = fmaxf(mx, __shfl_xor(mx, m));
  const float e = __expf(logit - mx);
  float ssum = e;
#pragma unroll
  for (int m = 16; m >= 1; m >>= 1) ssum += __shfl_xor(ssum, m);
  const float attn = e / ssum;

  // ---- sampling location + bilinear corner descriptors ----
  const float rx = loadx(refp, (size_t)(qg * 4 + l) * 2 + 0, f32m);
  const float ry = loadx(refp, (size_t)(qg * 4 + l) * 2 + 1, f32m);
  float ox, oy;
  if (p < 4) {
    ox = bf2f(prow[h * 32 + l * 8 + p * 2 + 0]) / Wf;
    oy = bf2f(prow[h * 32 + l * 8 + p * 2 + 1]) / THf;
  } else {
    const int pj = p - 4, tw = pj >> 1, j = pj & 1;
    ox = loadx(toff, (size_t)(qg * 4 + l) * 4 + tw * 2 + 0, f32m) +
         bf2f(prow[256 + h * 32 + l * 8 + tw * 4 + j * 2 + 0]) / Wf;
    oy = loadx(toff, (size_t)(qg * 4 + l) * 4 + tw * 2 + 1, f32m) +
         bf2f(prow[256 + h * 32 + l * 8 + tw * 4 + j * 2 + 1]) / THf;
  }
  const float x = (rx + ox) * Wf - 0.5f;   // grid_sample align_corners=False
  const float y = (ry + oy) * THf - 0.5f;
  const float x0f = floorf(x), y0f = floorf(y);
  const float lx = x - x0f, ly = y - y0f;
  const int x0 = (int)x0f, y0 = (int)y0f;
  const int Wg = W_i[l], THg = TH_i[l], ST = ST_i[l];
  const float cwx[2] = {1.f - lx, lx};
  const float cwy[2] = {1.f - ly, ly};
#pragma unroll
  for (int c = 0; c < 4; ++c) {
    const int xi = x0 + (c & 1), yi = y0 + (c >> 1);
    const bool inb = (xi >= 0) & (xi < Wg) & (yi >= 0) & (yi < THg);
    const int xc = min(max(xi, 0), Wg - 1);
    const int yc = min(max(yi, 0), THg - 1);
    s_idx[tid][c] = ST + yc * Wg + xc;
    s_w[tid][c] = inb ? (attn * cwx[c & 1] * cwy[c >> 1]) : 0.f;
  }
  __syncthreads();

  // ---- gather: thread = (qi, pt-group pg 0..7, ch-quad chq 0..3) ----
  {
    const int pg = sp >> 2;
    const int chq = sp & 3;
    const bfraw* vb = value + h * 32 + chq * 8;
    int   idx[16];
    float ww[16];
#pragma unroll
    for (int pt = 0; pt < 4; ++pt) {
      const int ds = qi * 32 + pg * 4 + pt;
#pragma unroll
      for (int c = 0; c < 4; ++c) { idx[pt * 4 + c] = s_idx[ds][c]; ww[pt * 4 + c] = s_w[ds][c]; }
    }
    uint4 vv[16];
#pragma unroll
    for (int i = 0; i < 16; ++i) vv[i] = *(const uint4*)(vb + (size_t)idx[i] * 256);
    float acc[8] = {};
#pragma unroll
    for (int i = 0; i < 16; ++i) {
      const float w = ww[i]; const uint4 v = vv[i];
      acc[0] += w * lo16f(v.x); acc[1] += w * hi16f(v.x);
      acc[2] += w * lo16f(v.y); acc[3] += w * hi16f(v.y);
      acc[4] += w * lo16f(v.z); acc[5] += w * hi16f(v.z);
      acc[6] += w * lo16f(v.w); acc[7] += w * hi16f(v.w);
    }
    // reduce over pg (lane bits 2..4 — stays within the 32-lane group)
#pragma unroll
    for (int m = 4; m <= 16; m <<= 1)
#pragma unroll
      for (int r = 0; r < 8; ++r)
        acc[r] += __shfl_xor(acc[r], m);
    if (pg == 0) {   // core overlay: prow[h*32 + chq*8 .. +8) := slice (bf16)
      uint4 pk;
      pk.x = pk2(acc[0], acc[1]);
      pk.y = pk2(acc[2], acc[3]);
      pk.z = pk2(acc[4], acc[5]);
      pk.w = pk2(acc[6], acc[7]);
      *(uint4*)(prow + h * 32 + chq * 8) = pk;
    }
  }
}

extern "C" void kernel_launch(void* const* d_in, const int* in_sizes, int n_in,
                              void* d_out, int out_size, void* d_ws, size_t ws_size,
                              hipStream_t stream)
{
  const void* query  = d_in[0];
  const void* refp   = d_in[1];
  const void* toff   = d_in[2];
  const void* inflat = d_in[3];
  const void* W_so  = d_in[6];
  const void* b_so  = d_in[7];
  const void* W_tso = d_in[8];
  const void* b_tso = d_in[9];
  const void* W_aw  = d_in[10];
  const void* b_aw  = d_in[11];
  const void* W_taw = d_in[12];
  const void* b_taw = d_in[13];
  const void* W_v   = d_in[14];
  const void* b_v   = d_in[15];
  const void* W_o   = d_in[16];
  const void* b_o   = d_in[17];

  const int Lq = 16320;
  // ws: WT bf16 [1280][256] | bcat f32[768] | value bf16 [Lq][256] |
  //     proj bf16 [Lq][768]  (~34.1 MB, proven footprint)
  const size_t WT_B   = (size_t)1280 * 256 * 2;
  const size_t BCAT_B = 768 * 4;
  const size_t VAL_B  = (size_t)Lq * 256 * 2;
  bfraw* WT    = (bfraw*)d_ws;
  float* bcat  = (float*)((char*)d_ws + WT_B);
  bfraw* value = (bfraw*)((char*)d_ws + WT_B + BCAT_B);
  bfraw* proj  = (bfraw*)((char*)d_ws + WT_B + BCAT_B + VAL_B);

  const dim3 blk(256);
  transpose_k<<<dim3(1283), blk, 0, stream>>>(W_v, W_so, W_tso, W_aw, W_taw, W_o,
                                              b_so, b_tso, b_aw, b_taw, WT, bcat, query);
  gemmVP_k<<<dim3(128, 8), blk, 0, stream>>>(inflat, query, WT, b_v, bcat, value, proj, Lq);
  sampler_k<<<dim3(Lq / 8, 4), blk, 0, stream>>>(proj, value, refp, toff, query, 0);
  sampler_k<<<dim3(Lq / 8, 4), blk, 0, stream>>>(proj, value, refp, toff, query, 4);
  gemmO_k<<<dim3(128, 2), blk, 0, stream>>>(proj, WT, b_o, d_out, query, Lq);
}